// Round 14
// baseline (181.116 us; speedup 1.0000x reference)
//
#include <hip/hip_runtime.h>
#include <hip/hip_bf16.h>

typedef unsigned short u16;
typedef unsigned int u32;
typedef __attribute__((ext_vector_type(8))) short bf16x8;
typedef __attribute__((ext_vector_type(4))) float f32x4;

#define D640 640

__device__ __forceinline__ float b2f(u16 u) {
  union { u32 i; float f; } x; x.i = ((u32)u) << 16; return x.f;
}
__device__ __forceinline__ u16 f2b(float f) {
  union { __hip_bfloat16 h; u16 u; } c; c.h = __float2bfloat16(f); return c.u;
}
__device__ __forceinline__ u32 pack2(float a, float b) {
  union { __hip_bfloat162 h; u32 u; } c;
  c.h.x = __float2bfloat16(a); c.h.y = __float2bfloat16(b); return c.u;
}
__device__ __forceinline__ bf16x8 pack8(f32x4 lo, f32x4 hi) {
  bf16x8 r;
  r[0] = (short)f2b(lo[0]); r[1] = (short)f2b(lo[1]);
  r[2] = (short)f2b(lo[2]); r[3] = (short)f2b(lo[3]);
  r[4] = (short)f2b(hi[0]); r[5] = (short)f2b(hi[1]);
  r[6] = (short)f2b(hi[2]); r[7] = (short)f2b(hi[3]);
  return r;
}
__device__ __forceinline__ void gld_lds16(const u16* g, u16* l) {
  __builtin_amdgcn_global_load_lds((const __attribute__((address_space(1))) u32*)g,
                                   (__attribute__((address_space(3))) u32*)l, 16, 0, 0);
}

// ------------- dtype detector: inputs bf16 (flag=0) or fp32 (flag=1)? -------------
__global__ void detect_dtype(const u16* __restrict__ hs, u32* __restrict__ flag) {
  __shared__ u32 cnt;
  if (threadIdx.x == 0) cnt = 0;
  __syncthreads();
  int plaus = 0;
#pragma unroll
  for (int i = 0; i < 16; ++i) {
    u16 u = hs[(threadIdx.x * 16 + i) * 2];
    u32 e = (u >> 7) & 0xFF;
    if ((e >= 0x70 && e <= 0x8F) || (u & 0x7FFF) == 0) plaus++;
  }
  atomicAdd(&cnt, (u32)plaus);
  __syncthreads();
  if (threadIdx.x == 0) *flag = (cnt < 2048) ? 1u : 0u;
}

// ------------------- transpose (+convert) the 4 weight matrices -> bf16 -------------------
__global__ __launch_bounds__(256) void transpose_w(
    const void* __restrict__ w0, const void* __restrict__ w1,
    const void* __restrict__ w2, const void* __restrict__ w3,
    u16* __restrict__ out, const u32* __restrict__ flag)
{
  __shared__ u16 t[32][33];
  const bool isF32 = (*flag != 0);
  const void* src = blockIdx.z == 0 ? w0 : blockIdx.z == 1 ? w1 : blockIdx.z == 2 ? w2 : w3;
  u16* dst = out + (size_t)blockIdx.z * 409600;
  int tx = threadIdx.x, ty = threadIdx.y;
  int x = blockIdx.x * 32 + tx;
  int y = blockIdx.y * 32 + ty;
  if (isF32) {
    const float* s = (const float*)src;
#pragma unroll
    for (int j = 0; j < 32; j += 8) t[ty + j][tx] = f2b(s[(y + j) * D640 + x]);
  } else {
    const u16* s = (const u16*)src;
#pragma unroll
    for (int j = 0; j < 32; j += 8) t[ty + j][tx] = s[(y + j) * D640 + x];
  }
  __syncthreads();
  int x2 = blockIdx.y * 32 + tx;
  int y2 = blockIdx.x * 32 + ty;
#pragma unroll
  for (int j = 0; j < 32; j += 8) dst[(y2 + j) * D640 + x2] = t[tx][ty + j];
}

// -------- gemm_qkv: merged Q + K + V projections, one 640-block dispatch --------
// BM=128, BN=160, BK=32; 4 waves (2x2), wave tile 64x80.
// A: fp32 (or bf16) reg-staged with XOR-swizzled ds_write (r11-proven).
// B: bf16 weights via global_load_lds w=16, swizzled-SOURCE + linear LDS (r12-proven).
// bid < 512: Q (cMode 0, scale=QSCALE). bid>=512: K (cMode 0) / V (cMode 2, key-perm V^T).
__global__ __launch_bounds__(256) void gemm_qkv(
    const void* __restrict__ hsv, const u16* __restrict__ WT,
    u16* __restrict__ Qb, u16* __restrict__ Kb, u16* __restrict__ Vb,
    const u32* __restrict__ flag, float qscale)
{
  __shared__ __align__(16) u16 Asub[128 * 32];
  __shared__ __align__(16) u16 Bsub[160 * 32];
  const bool aF32 = (*flag != 0);
  const int tid = threadIdx.x;
  const int lane = tid & 63, w = tid >> 6;
  const int wr = w >> 1, wc = w & 1;
  const int l15 = lane & 15, g = lane >> 4;

  // decode operation
  const int bid = blockIdx.x;
  int bx, by, aRow0, cMode;
  const u16* BT;
  u16* Cv;
  float scale;
  if (bid < 512) {
    bx = bid >> 2; by = bid & 3; aRow0 = 0; cMode = 0;
    BT = WT; Cv = Qb; scale = qscale;
  } else {
    const int t = bid - 512;          // 0..127
    const bool isK = (t < 64);
    const int t2 = t & 63;
    const int grp = t2 >> 5;
    bx = (t2 >> 2) & 7; by = t2 & 3; aRow0 = grp * 8192;
    cMode = isK ? 0 : 2;
    BT = isK ? (WT + 409600) : (WT + 819200);
    Cv = isK ? (Kb + (size_t)grp * 655360) : (Vb + (size_t)grp * 655360);
    scale = 1.f;
  }
  const int rowBase = bx * 128;
  const int colBase = by * 160;

  // A reg-staging: 512 chunks, 2/thread, XOR-swizzled slots
  const int ar0 = tid >> 2, ar1 = ar0 + 64, gc = tid & 3;
  const int als0 = ar0 * 4 + (gc ^ ((ar0 >> 1) & 3));
  const int als1 = ar1 * 4 + (gc ^ ((ar1 >> 1) & 3));
  const size_t aIdx0 = (size_t)(aRow0 + rowBase + ar0) * D640 + gc * 8;
  const size_t aIdx1 = (size_t)(aRow0 + rowBase + ar1) * D640 + gc * 8;

  // B gld_lds: 640 chunks; chunk c holds global (row=c>>2, kc=(c&3)^((c>>3)&3)), LDS linear
  const int bc0 = w * 64 + lane;            // pass 0: chunks 0..255
  const int bc1 = bc0 + 256;                // pass 1: chunks 256..511
  const int bc2 = 512 + w * 64 + lane;      // pass 2 (waves 0-1): 512..639
  const u16* Bg0 = BT + (size_t)(colBase + (bc0 >> 2)) * D640 + ((bc0 & 3) ^ ((bc0 >> 3) & 3)) * 8;
  const u16* Bg1 = BT + (size_t)(colBase + (bc1 >> 2)) * D640 + ((bc1 & 3) ^ ((bc1 >> 3) & 3)) * 8;
  const u16* Bg2 = BT + (size_t)(colBase + ((bc2 >> 2) & 255)) * D640 + ((bc2 & 3) ^ ((bc2 >> 3) & 3)) * 8;
  u16* lB0 = &Bsub[(size_t)w * 64 * 8];
  u16* lB1 = &Bsub[((size_t)w * 64 + 256) * 8];
  u16* lB2 = &Bsub[((size_t)w * 64 + 512) * 8];

  int aoff[4], boff[5];
#pragma unroll
  for (int f = 0; f < 4; ++f) {
    int R = wr * 64 + f * 16 + l15;
    aoff[f] = (R * 4 + (g ^ ((R >> 1) & 3))) * 8;
  }
#pragma unroll
  for (int j = 0; j < 5; ++j) {
    int Cc = wc * 80 + j * 16 + l15;
    boff[j] = (Cc * 4 + (g ^ ((Cc >> 1) & 3))) * 8;
  }

  f32x4 acc[4][5];
#pragma unroll
  for (int i = 0; i < 4; ++i)
#pragma unroll
    for (int j = 0; j < 5; ++j) acc[i][j] = (f32x4){0.f, 0.f, 0.f, 0.f};

  bf16x8 ra0, ra1;
  if (aF32) {
    const float* Af = (const float*)hsv;
    ra0 = pack8(*(const f32x4*)(Af + aIdx0), *(const f32x4*)(Af + aIdx0 + 4));
    ra1 = pack8(*(const f32x4*)(Af + aIdx1), *(const f32x4*)(Af + aIdx1 + 4));
  } else {
    const u16* Ab = (const u16*)hsv;
    ra0 = *(const bf16x8*)(Ab + aIdx0);
    ra1 = *(const bf16x8*)(Ab + aIdx1);
  }

  for (int kt = 0; kt < 20; ++kt) {
    __syncthreads();
    *(bf16x8*)&Asub[als0 * 8] = ra0;
    *(bf16x8*)&Asub[als1 * 8] = ra1;
    gld_lds16(Bg0 + kt * 32, lB0);
    gld_lds16(Bg1 + kt * 32, lB1);
    if (w < 2) gld_lds16(Bg2 + kt * 32, lB2);
    __syncthreads();   // drains vmcnt + lgkm before any frag read
    if (kt < 19) {
      const int k1 = (kt + 1) * 32;
      if (aF32) {
        const float* Af = (const float*)hsv;
        ra0 = pack8(*(const f32x4*)(Af + aIdx0 + k1), *(const f32x4*)(Af + aIdx0 + k1 + 4));
        ra1 = pack8(*(const f32x4*)(Af + aIdx1 + k1), *(const f32x4*)(Af + aIdx1 + k1 + 4));
      } else {
        const u16* Ab = (const u16*)hsv;
        ra0 = *(const bf16x8*)(Ab + aIdx0 + k1);
        ra1 = *(const bf16x8*)(Ab + aIdx1 + k1);
      }
    }
    bf16x8 a[4], b[5];
#pragma unroll
    for (int f = 0; f < 4; ++f) a[f] = *(const bf16x8*)&Asub[aoff[f]];
#pragma unroll
    for (int j = 0; j < 5; ++j) b[j] = *(const bf16x8*)&Bsub[boff[j]];
    __builtin_amdgcn_s_setprio(1);
#pragma unroll
    for (int i = 0; i < 4; ++i)
#pragma unroll
      for (int j = 0; j < 5; ++j)
        acc[i][j] = __builtin_amdgcn_mfma_f32_16x16x32_bf16(a[i], b[j], acc[i][j], 0, 0, 0);
    __builtin_amdgcn_s_setprio(0);
  }

#pragma unroll
  for (int j = 0; j < 5; ++j) {
    int col = colBase + wc * 80 + j * 16 + l15;
#pragma unroll
    for (int i = 0; i < 4; ++i) {
      int row = rowBase + wr * 64 + i * 16 + g * 4;
#pragma unroll
      for (int r = 0; r < 4; ++r) {
        float v = acc[i][j][r] * scale;
        if (cMode == 2) {
          int rw = row + r;
          int rl = rw & 63;
          int slot = (rl & 32) | ((rl & 12) << 1) | (((rl >> 4) & 1) << 2) | (rl & 3);
          ((u16*)Cv)[(size_t)col * 1024 + (rw & ~63) + slot] = f2b(v);
        } else {
          ((u16*)Cv)[(size_t)(row + r) * D640 + col] = f2b(v);  // r13 bug: was row*D640
        }
      }
    }
  }
}

// ---------- gemm3: m97-style 128x128 bf16 GEMM via global_load_lds (out-proj) ----------
__global__ __launch_bounds__(256) void gemm3(
    const u16* __restrict__ A, const u16* __restrict__ BT, void* __restrict__ Cv,
    float scale, const void* __restrict__ bias, const u32* __restrict__ flag,
    int aRow0, int cMode)
{
  __shared__ __align__(16) u16 Asub[128 * 32];
  __shared__ __align__(16) u16 Bsub[128 * 32];
  const bool isF32 = (*flag != 0);
  const bool cF32 = (cMode == 1) && isF32;
  const int tid = threadIdx.x;
  const int lane = tid & 63, w = tid >> 6;
  const int wr = w >> 1, wc = w & 1;
  const int l15 = lane & 15, g = lane >> 4;
  const int rowBase = blockIdx.x * 128;
  const int colBase = blockIdx.y * 128;

  const int c0 = w * 128 + lane, c1 = c0 + 64;
  const u16* Ag0 = A + (size_t)(aRow0 + rowBase + (c0 >> 2)) * D640 + ((c0 & 3) ^ ((c0 >> 3) & 3)) * 8;
  const u16* Ag1 = A + (size_t)(aRow0 + rowBase + (c1 >> 2)) * D640 + ((c1 & 3) ^ ((c1 >> 3) & 3)) * 8;
  const u16* Bg0 = BT + (size_t)(colBase + (c0 >> 2)) * D640 + ((c0 & 3) ^ ((c0 >> 3) & 3)) * 8;
  const u16* Bg1 = BT + (size_t)(colBase + (c1 >> 2)) * D640 + ((c1 & 3) ^ ((c1 >> 3) & 3)) * 8;
  u16* lA0 = &Asub[w * 1024];
  u16* lA1 = &Asub[w * 1024 + 512];
  u16* lB0 = &Bsub[w * 1024];
  u16* lB1 = &Bsub[w * 1024 + 512];

  int aoff[4], boff[4];
#pragma unroll
  for (int f = 0; f < 4; ++f) {
    int R = wr * 64 + f * 16 + l15;
    aoff[f] = (R * 4 + (g ^ ((R >> 1) & 3))) * 8;
    int Cc = wc * 64 + f * 16 + l15;
    boff[f] = (Cc * 4 + (g ^ ((Cc >> 1) & 3))) * 8;
  }

  f32x4 acc[4][4];
#pragma unroll
  for (int i = 0; i < 4; ++i)
#pragma unroll
    for (int j = 0; j < 4; ++j) acc[i][j] = (f32x4){0.f, 0.f, 0.f, 0.f};

  for (int kt = 0; kt < 20; ++kt) {
    __syncthreads();
    gld_lds16(Ag0 + kt * 32, lA0);
    gld_lds16(Ag1 + kt * 32, lA1);
    gld_lds16(Bg0 + kt * 32, lB0);
    gld_lds16(Bg1 + kt * 32, lB1);
    __syncthreads();
    bf16x8 a[4], b[4];
#pragma unroll
    for (int f = 0; f < 4; ++f) a[f] = *(const bf16x8*)&Asub[aoff[f]];
#pragma unroll
    for (int f = 0; f < 4; ++f) b[f] = *(const bf16x8*)&Bsub[boff[f]];
    __builtin_amdgcn_s_setprio(1);
#pragma unroll
    for (int i = 0; i < 4; ++i)
#pragma unroll
      for (int j = 0; j < 4; ++j)
        acc[i][j] = __builtin_amdgcn_mfma_f32_16x16x32_bf16(a[i], b[j], acc[i][j], 0, 0, 0);
    __builtin_amdgcn_s_setprio(0);
  }

#pragma unroll
  for (int j = 0; j < 4; ++j) {
    int col = colBase + wc * 64 + j * 16 + l15;
    float bb = 0.f;
    if (bias) bb = cF32 ? ((const float*)bias)[col] : b2f(((const u16*)bias)[col]);
#pragma unroll
    for (int i = 0; i < 4; ++i) {
      int row = rowBase + wr * 64 + i * 16 + g * 4;
#pragma unroll
      for (int r = 0; r < 4; ++r) {
        float v = acc[i][j][r] * scale + bb;
        if (cF32) ((float*)Cv)[(size_t)(row + r) * D640 + col] = v;
        else      ((u16*)Cv)[(size_t)(row + r) * D640 + col] = f2b(v);
      }
    }
  }
}

// ------------------- flash attention v7 (r12, unchanged: 89.2us) -------------------
__global__ __launch_bounds__(256, 3) void attn_kernel(
    const u16* __restrict__ Q, const u16* __restrict__ K2,
    const u16* __restrict__ VT, u16* __restrict__ AO)
{
  __shared__ __align__(16) u16 Klds[64 * 104];
  __shared__ __align__(16) u16 Vlds[80 * 72];

  const int tid = threadIdx.x, lane = tid & 63, w = tid >> 6;
  const int l15 = lane & 15, g = lane >> 4;
  const int qc = blockIdx.x, bh = blockIdx.y;
  const int f = bh >> 3, h = bh & 7;
  const int grp = f >> 3;

  const u16* Qp = Q + (size_t)(f * 1024 + qc * 128 + w * 32) * D640 + h * 80;
  const u16* Kp = K2 + (size_t)(grp * 1024) * D640 + h * 80;
  const u16* Vp = VT + (size_t)(grp * 8 + h) * 80 * 1024;

  if (tid < 128) {
    const bf16x8 z8 = {0, 0, 0, 0, 0, 0, 0, 0};
    *(bf16x8*)&Klds[(tid >> 1) * 104 + 80 + (tid & 1) * 8] = z8;
  }

  bf16x8 qreg[2][3];
#pragma unroll
  for (int qb = 0; qb < 2; ++qb)
#pragma unroll
    for (int dc = 0; dc < 3; ++dc) {
      int dd = dc * 32 + g * 8;
      if (dd < 80) qreg[qb][dc] = *(const bf16x8*)(Qp + (l15 + 16 * qb) * D640 + dd);
      else         qreg[qb][dc] = (bf16x8){0, 0, 0, 0, 0, 0, 0, 0};
    }

  f32x4 acc[2][5];
#pragma unroll
  for (int qb = 0; qb < 2; ++qb)
#pragma unroll
    for (int db = 0; db < 5; ++db) acc[qb][db] = (f32x4){0.f, 0.f, 0.f, 0.f};
  float mreg[2] = {0.f, 0.f};
  float lrow[2] = {0.f, 0.f};

  const u16* gsrc[5];
  u16* ldst[5];
  int step[5];
#pragma unroll
  for (int i = 0; i < 5; ++i) {
    int c = tid + i * 256;
    if (c < 640) {
      int row = c / 10, cc = c - row * 10;
      gsrc[i] = Kp + row * D640 + cc * 8;
      ldst[i] = &Klds[row * 104 + cc * 8];
      step[i] = 64 * D640;
    } else {
      int c2 = c - 640, d = c2 >> 3, cc = c2 & 7;
      gsrc[i] = Vp + d * 1024 + cc * 8;
      ldst[i] = &Vlds[d * 72 + cc * 8];
      step[i] = 64;
    }
  }

  bf16x8 pre[5];
#pragma unroll
  for (int i = 0; i < 5; ++i) pre[i] = *(const bf16x8*)gsrc[i];

  for (int it = 0; it < 16; ++it) {
    __syncthreads();
#pragma unroll
    for (int i = 0; i < 5; ++i) *(bf16x8*)ldst[i] = pre[i];
    __syncthreads();
    if (it < 15) {
#pragma unroll
      for (int i = 0; i < 5; ++i) pre[i] = *(const bf16x8*)(gsrc[i] + (it + 1) * step[i]);
    }

    f32x4 st[4][2];
#pragma unroll
    for (int kb = 0; kb < 4; ++kb)
#pragma unroll
      for (int qb = 0; qb < 2; ++qb) st[kb][qb] = (f32x4){0.f, 0.f, 0.f, 0.f};
    __builtin_amdgcn_s_setprio(1);
#pragma unroll
    for (int dc = 0; dc < 3; ++dc)
#pragma unroll
      for (int kb = 0; kb < 4; ++kb) {
        bf16x8 ka = *(const bf16x8*)&Klds[(kb * 16 + l15) * 104 + dc * 32 + g * 8];
        st[kb][0] = __builtin_amdgcn_mfma_f32_16x16x32_bf16(ka, qreg[0][dc], st[kb][0], 0, 0, 0);
        st[kb][1] = __builtin_amdgcn_mfma_f32_16x16x32_bf16(ka, qreg[1][dc], st[kb][1], 0, 0, 0);
      }
    __builtin_amdgcn_s_setprio(0);

    float mt[2];
#pragma unroll
    for (int qb = 0; qb < 2; ++qb) {
      float m01 = fmaxf(fmaxf(st[0][qb][0], st[0][qb][1]), fmaxf(st[0][qb][2], st[0][qb][3]));
      float m23 = fmaxf(fmaxf(st[1][qb][0], st[1][qb][1]), fmaxf(st[1][qb][2], st[1][qb][3]));
      float m45 = fmaxf(fmaxf(st[2][qb][0], st[2][qb][1]), fmaxf(st[2][qb][2], st[2][qb][3]));
      float m67 = fmaxf(fmaxf(st[3][qb][0], st[3][qb][1]), fmaxf(st[3][qb][2], st[3][qb][3]));
      mt[qb] = fmaxf(fmaxf(m01, m23), fmaxf(m45, m67));
    }

    if (__any((mt[0] > mreg[0] + 8.f) || (mt[1] > mreg[1] + 8.f))) {
#pragma unroll
      for (int qb = 0; qb < 2; ++qb) {
        float m = mt[qb];
        m = fmaxf(m, __shfl_xor(m, 16, 64));
        m = fmaxf(m, __shfl_xor(m, 32, 64));
        float mn = fmaxf(mreg[qb], m);
        float scl = exp2f(mreg[qb] - mn);
        mreg[qb] = mn;
        lrow[qb] *= scl;
        float s_[4];
#pragma unroll
        for (int r = 0; r < 4; ++r)
          s_[r] = __shfl(scl, (lane & 48) | (g * 4 + r), 64);
#pragma unroll
        for (int db = 0; db < 5; ++db)
#pragma unroll
          for (int r = 0; r < 4; ++r) acc[qb][db][r] *= s_[r];
      }
    }

    bf16x8 pa[2][2];
#pragma unroll
    for (int qb = 0; qb < 2; ++qb) {
      float sum = 0.f;
      u32 wlo[4], whi[4];
#pragma unroll
      for (int kb = 0; kb < 4; ++kb) {
        float p0 = exp2f(st[kb][qb][0] - mreg[qb]);
        float p1 = exp2f(st[kb][qb][1] - mreg[qb]);
        float p2 = exp2f(st[kb][qb][2] - mreg[qb]);
        float p3 = exp2f(st[kb][qb][3] - mreg[qb]);
        sum += (p0 + p1) + (p2 + p3);
        wlo[kb] = pack2(p0, p1);
        whi[kb] = pack2(p2, p3);
      }
      lrow[qb] += sum;
#pragma unroll
      for (int kc = 0; kc < 2; ++kc) {
        union { u32 u[4]; bf16x8 v; } cvt;
        cvt.u[0] = wlo[2 * kc];
        cvt.u[1] = whi[2 * kc];
        cvt.u[2] = wlo[2 * kc + 1];
        cvt.u[3] = whi[2 * kc + 1];
        pa[qb][kc] = cvt.v;
      }
    }

    __builtin_amdgcn_s_setprio(1);
#pragma unroll
    for (int kc = 0; kc < 2; ++kc) {
#pragma unroll
      for (int db = 0; db < 5; ++db) {
        bf16x8 bv = *(const bf16x8*)&Vlds[(db * 16 + l15) * 72 + kc * 32 + g * 8];
        acc[0][db] = __builtin_amdgcn_mfma_f32_16x16x32_bf16(pa[0][kc], bv, acc[0][db], 0, 0, 0);
        acc[1][db] = __builtin_amdgcn_mfma_f32_16x16x32_bf16(pa[1][kc], bv, acc[1][db], 0, 0, 0);
      }
    }
    __builtin_amdgcn_s_setprio(0);
  }

  u16* Op = AO + (size_t)(f * 1024 + qc * 128 + w * 32) * D640 + h * 80;
#pragma unroll
  for (int qb = 0; qb < 2; ++qb) {
    float lr = lrow[qb];
    lr += __shfl_xor(lr, 16, 64);
    lr += __shfl_xor(lr, 32, 64);
    float i_[4];
#pragma unroll
    for (int r = 0; r < 4; ++r)
      i_[r] = 1.f / __shfl(lr, (lane & 48) | (g * 4 + r), 64);
#pragma unroll
    for (int db = 0; db < 5; ++db)
#pragma unroll
      for (int r = 0; r < 4; ++r)
        Op[(qb * 16 + g * 4 + r) * D640 + db * 16 + l15] = f2b(acc[qb][db][r] * i_[r]);
  }
}

// ------------------- launcher -------------------
extern "C" void kernel_launch(void* const* d_in, const int* in_sizes, int n_in,
                              void* d_out, int out_size, void* d_ws, size_t ws_size,
                              hipStream_t stream) {
  (void)in_sizes; (void)n_in; (void)out_size; (void)ws_size;
  const void* hs = d_in[0];
  const void* wq = d_in[1];
  const void* wk = d_in[2];
  const void* wv = d_in[3];
  const void* wo = d_in[4];
  const void* bo = d_in[5];
  u16* ws = (u16*)d_ws;

  u16* WT  = ws;                         // 4 * 640*640           bf16
  u16* Qb  = ws + 1638400;               // 16384*640             bf16
  u16* Kb  = Qb + 10485760;              // 2048*640              bf16
  u16* Vb  = Kb + 1310720;               // V^T key-permuted: 2 grp x [640][1024]
  u16* AOb = Vb + 1310720;               // 16384*640             bf16
  u32* flag = (u32*)(AOb + 10485760);    // dtype flag

  const float QSCALE = 0.11180339887498949f * 1.44269504088896340f;

  detect_dtype<<<1, 256, 0, stream>>>((const u16*)hs, flag);
  transpose_w<<<dim3(20, 20, 4), dim3(32, 8), 0, stream>>>(wq, wk, wv, wo, WT, flag);

  // Q + K + V projections in one dispatch (Q: 512 blocks; K/V: 128)
  gemm_qkv<<<640, 256, 0, stream>>>(hs, WT, Qb, Kb, Vb, flag, QSCALE);

  attn_kernel<<<dim3(8, 128), 256, 0, stream>>>(Qb, Kb, Vb, AOb);

  // output projection + bias; C dtype follows detected input dtype
  gemm3<<<dim3(128, 5), 256, 0, stream>>>(AOb, WT + 1228800, d_out, 1.f, bo, flag, 0, 1);
}

// Round 15
// 164.303 us; speedup vs baseline: 1.1023x; 1.1023x over previous
//
#include <hip/hip_runtime.h>
#include <hip/hip_bf16.h>

typedef unsigned short u16;
typedef unsigned int u32;
typedef __attribute__((ext_vector_type(8))) short bf16x8;
typedef __attribute__((ext_vector_type(4))) float f32x4;

#define D640 640

__device__ __forceinline__ float b2f(u16 u) {
  union { u32 i; float f; } x; x.i = ((u32)u) << 16; return x.f;
}
__device__ __forceinline__ u16 f2b(float f) {
  union { __hip_bfloat16 h; u16 u; } c; c.h = __float2bfloat16(f); return c.u;
}
__device__ __forceinline__ u32 pack2(float a, float b) {
  union { __hip_bfloat162 h; u32 u; } c;
  c.h.x = __float2bfloat16(a); c.h.y = __float2bfloat16(b); return c.u;
}
__device__ __forceinline__ bf16x8 pack8(f32x4 lo, f32x4 hi) {
  bf16x8 r;
  r[0] = (short)f2b(lo[0]); r[1] = (short)f2b(lo[1]);
  r[2] = (short)f2b(lo[2]); r[3] = (short)f2b(lo[3]);
  r[4] = (short)f2b(hi[0]); r[5] = (short)f2b(hi[1]);
  r[6] = (short)f2b(hi[2]); r[7] = (short)f2b(hi[3]);
  return r;
}
__device__ __forceinline__ void gld_lds16(const u16* g, u16* l) {
  __builtin_amdgcn_global_load_lds((const __attribute__((address_space(1))) u32*)g,
                                   (__attribute__((address_space(3))) u32*)l, 16, 0, 0);
}

// ------------- dtype detector: inputs bf16 (flag=0) or fp32 (flag=1)? -------------
__global__ void detect_dtype(const u16* __restrict__ hs, u32* __restrict__ flag) {
  __shared__ u32 cnt;
  if (threadIdx.x == 0) cnt = 0;
  __syncthreads();
  int plaus = 0;
#pragma unroll
  for (int i = 0; i < 16; ++i) {
    u16 u = hs[(threadIdx.x * 16 + i) * 2];
    u32 e = (u >> 7) & 0xFF;
    if ((e >= 0x70 && e <= 0x8F) || (u & 0x7FFF) == 0) plaus++;
  }
  atomicAdd(&cnt, (u32)plaus);
  __syncthreads();
  if (threadIdx.x == 0) *flag = (cnt < 2048) ? 1u : 0u;
}

// ------------------- transpose (+convert) the 4 weight matrices -> bf16 -------------------
__global__ __launch_bounds__(256) void transpose_w(
    const void* __restrict__ w0, const void* __restrict__ w1,
    const void* __restrict__ w2, const void* __restrict__ w3,
    u16* __restrict__ out, const u32* __restrict__ flag)
{
  __shared__ u16 t[32][33];
  const bool isF32 = (*flag != 0);
  const void* src = blockIdx.z == 0 ? w0 : blockIdx.z == 1 ? w1 : blockIdx.z == 2 ? w2 : w3;
  u16* dst = out + (size_t)blockIdx.z * 409600;
  int tx = threadIdx.x, ty = threadIdx.y;
  int x = blockIdx.x * 32 + tx;
  int y = blockIdx.y * 32 + ty;
  if (isF32) {
    const float* s = (const float*)src;
#pragma unroll
    for (int j = 0; j < 32; j += 8) t[ty + j][tx] = f2b(s[(y + j) * D640 + x]);
  } else {
    const u16* s = (const u16*)src;
#pragma unroll
    for (int j = 0; j < 32; j += 8) t[ty + j][tx] = s[(y + j) * D640 + x];
  }
  __syncthreads();
  int x2 = blockIdx.y * 32 + tx;
  int y2 = blockIdx.x * 32 + ty;
#pragma unroll
  for (int j = 0; j < 32; j += 8) dst[(y2 + j) * D640 + x2] = t[tx][ty + j];
}

// ------------------- 128x128-tile bf16 GEMM body (K/V projections; r11-proven) ----------
// cMode: 0 bf16 [row][640];
//        2 bf16 V^T KEY-PERMUTED: slot (k&32)|((k&12)<<1)|(((k>>4)&1)<<2)|(k&3)
__device__ __forceinline__ void gemm_body(
    const void* __restrict__ Av, const u16* __restrict__ BT, void* __restrict__ Cv,
    float scale, bool isF32, int aRow0, int cMode, int bx, int by)
{
  __shared__ __align__(16) u16 Asub[128 * 32];
  __shared__ __align__(16) u16 Bsub[128 * 32];
  const bool aF32 = isF32;
  const int tid = threadIdx.x;
  const int lane = tid & 63, w = tid >> 6;
  const int wr = w >> 1, wc = w & 1;
  const int l15 = lane & 15, g = lane >> 4;
  const int rowBase = bx * 128;
  const int colBase = by * 128;

  const int r0 = tid >> 2, r1 = r0 + 64, gc = tid & 3;
  const int ls0 = r0 * 4 + (gc ^ ((r0 >> 1) & 3));
  const int ls1 = r1 * 4 + (gc ^ ((r1 >> 1) & 3));
  const size_t aIdx0 = (size_t)(aRow0 + rowBase + r0) * D640 + gc * 8;
  const size_t aIdx1 = (size_t)(aRow0 + rowBase + r1) * D640 + gc * 8;
  const u16* Bg0 = BT + (colBase + r0) * D640 + gc * 8;
  const u16* Bg1 = BT + (colBase + r1) * D640 + gc * 8;

  int aoff[4], boff[4];
#pragma unroll
  for (int f = 0; f < 4; ++f) {
    int R = wr * 64 + f * 16 + l15;
    aoff[f] = (R * 4 + (g ^ ((R >> 1) & 3))) * 8;
    int Cc = wc * 64 + f * 16 + l15;
    boff[f] = (Cc * 4 + (g ^ ((Cc >> 1) & 3))) * 8;
  }

  f32x4 acc[4][4];
#pragma unroll
  for (int i = 0; i < 4; ++i)
#pragma unroll
    for (int j = 0; j < 4; ++j) acc[i][j] = (f32x4){0.f, 0.f, 0.f, 0.f};

  bf16x8 ra0, ra1, rb0, rb1;
  if (aF32) {
    const float* Af = (const float*)Av;
    ra0 = pack8(*(const f32x4*)(Af + aIdx0), *(const f32x4*)(Af + aIdx0 + 4));
    ra1 = pack8(*(const f32x4*)(Af + aIdx1), *(const f32x4*)(Af + aIdx1 + 4));
  } else {
    const u16* Ab = (const u16*)Av;
    ra0 = *(const bf16x8*)(Ab + aIdx0);
    ra1 = *(const bf16x8*)(Ab + aIdx1);
  }
  rb0 = *(const bf16x8*)Bg0;
  rb1 = *(const bf16x8*)Bg1;

  for (int kt = 0; kt < 20; ++kt) {
    __syncthreads();
    *(bf16x8*)&Asub[ls0 * 8] = ra0;
    *(bf16x8*)&Asub[ls1 * 8] = ra1;
    *(bf16x8*)&Bsub[ls0 * 8] = rb0;
    *(bf16x8*)&Bsub[ls1 * 8] = rb1;
    __syncthreads();
    if (kt < 19) {
      const int k1 = (kt + 1) * 32;
      if (aF32) {
        const float* Af = (const float*)Av;
        ra0 = pack8(*(const f32x4*)(Af + aIdx0 + k1), *(const f32x4*)(Af + aIdx0 + k1 + 4));
        ra1 = pack8(*(const f32x4*)(Af + aIdx1 + k1), *(const f32x4*)(Af + aIdx1 + k1 + 4));
      } else {
        const u16* Ab = (const u16*)Av;
        ra0 = *(const bf16x8*)(Ab + aIdx0 + k1);
        ra1 = *(const bf16x8*)(Ab + aIdx1 + k1);
      }
      rb0 = *(const bf16x8*)(Bg0 + k1);
      rb1 = *(const bf16x8*)(Bg1 + k1);
    }
    bf16x8 a[4], b[4];
#pragma unroll
    for (int f = 0; f < 4; ++f) a[f] = *(const bf16x8*)&Asub[aoff[f]];
#pragma unroll
    for (int f = 0; f < 4; ++f) b[f] = *(const bf16x8*)&Bsub[boff[f]];
    __builtin_amdgcn_s_setprio(1);
#pragma unroll
    for (int i = 0; i < 4; ++i)
#pragma unroll
      for (int j = 0; j < 4; ++j)
        acc[i][j] = __builtin_amdgcn_mfma_f32_16x16x32_bf16(a[i], b[j], acc[i][j], 0, 0, 0);
    __builtin_amdgcn_s_setprio(0);
  }

#pragma unroll
  for (int j = 0; j < 4; ++j) {
    int col = colBase + wc * 64 + j * 16 + l15;
#pragma unroll
    for (int i = 0; i < 4; ++i) {
      int row = rowBase + wr * 64 + i * 16 + g * 4;
#pragma unroll
      for (int r = 0; r < 4; ++r) {
        float v = acc[i][j][r] * scale;
        if (cMode == 2) {
          int rw = row + r;
          int rl = rw & 63;
          int slot = (rl & 32) | ((rl & 12) << 1) | (((rl >> 4) & 1) << 2) | (rl & 3);
          ((u16*)Cv)[(size_t)col * 1024 + (rw & ~63) + slot] = f2b(v);
        } else {
          ((u16*)Cv)[(size_t)(row + r) * D640 + col] = f2b(v);
        }
      }
    }
  }
}

// merged K/V projection: z = 0: K grp0, 1: K grp1, 2: V grp0 (perm V^T), 3: V grp1
__global__ __launch_bounds__(256) void gemm_kv(
    const void* __restrict__ hs, const u16* __restrict__ WTk, const u16* __restrict__ WTv,
    u16* __restrict__ Kb, u16* __restrict__ Vb, const u32* __restrict__ flag)
{
  const int z = blockIdx.z;
  const bool isK = (z < 2);
  const int grp = z & 1;
  const u16* bt = isK ? WTk : WTv;
  void* cv = isK ? (void*)(Kb + (size_t)grp * 655360)
                 : (void*)(Vb + (size_t)grp * 655360);
  gemm_body(hs, bt, cv, 1.f, (*flag != 0), grp * 8192, isK ? 0 : 2,
            blockIdx.x, blockIdx.y);
}

// ------------------- gemm2: BM=128, BN=160 bf16 GEMM (Q-projection; r10-proven) ------
__global__ __launch_bounds__(256) void gemm2(
    const void* __restrict__ Av, const u16* __restrict__ BT, void* __restrict__ Cv,
    float scale, const void* __restrict__ bias, const u32* __restrict__ flag,
    int aF32mode, int cF32mode)
{
  __shared__ __align__(16) u16 Asub[128 * 32];
  __shared__ __align__(16) u16 Bsub[160 * 32];
  const bool isF32 = (*flag != 0);
  const bool aF32 = aF32mode && isF32;
  const bool cF32 = cF32mode && isF32;
  const int tid = threadIdx.x;
  const int lane = tid & 63, w = tid >> 6;
  const int wr = w >> 1, wc = w & 1;
  const int l15 = lane & 15, g = lane >> 4;
  const int rowBase = blockIdx.x * 128;
  const int colBase = blockIdx.y * 160;

  const int ar0 = tid >> 2, ar1 = ar0 + 64, gc = tid & 3;
  const int als0 = ar0 * 4 + (gc ^ ((ar0 >> 1) & 3));
  const int als1 = ar1 * 4 + (gc ^ ((ar1 >> 1) & 3));
  const size_t aIdx0 = (size_t)(rowBase + ar0) * D640 + gc * 8;
  const size_t aIdx1 = (size_t)(rowBase + ar1) * D640 + gc * 8;
  const bool hasB3 = (tid < 128);
  const int br0 = ar0, br1 = ar1, br2 = hasB3 ? (128 + (tid >> 2)) : 0;
  const int bls0 = als0, bls1 = als1;
  const int bls2 = br2 * 4 + (gc ^ ((br2 >> 1) & 3));
  const u16* Bg0 = BT + (colBase + br0) * D640 + gc * 8;
  const u16* Bg1 = BT + (colBase + br1) * D640 + gc * 8;
  const u16* Bg2 = BT + (colBase + br2) * D640 + gc * 8;

  int aoff[4], boff[5];
#pragma unroll
  for (int f = 0; f < 4; ++f) {
    int R = wr * 64 + f * 16 + l15;
    aoff[f] = (R * 4 + (g ^ ((R >> 1) & 3))) * 8;
  }
#pragma unroll
  for (int j = 0; j < 5; ++j) {
    int Cc = wc * 80 + j * 16 + l15;
    boff[j] = (Cc * 4 + (g ^ ((Cc >> 1) & 3))) * 8;
  }

  f32x4 acc[4][5];
#pragma unroll
  for (int i = 0; i < 4; ++i)
#pragma unroll
    for (int j = 0; j < 5; ++j) acc[i][j] = (f32x4){0.f, 0.f, 0.f, 0.f};

  bf16x8 ra0, ra1, rb0, rb1, rb2;
  if (aF32) {
    const float* Af = (const float*)Av;
    ra0 = pack8(*(const f32x4*)(Af + aIdx0), *(const f32x4*)(Af + aIdx0 + 4));
    ra1 = pack8(*(const f32x4*)(Af + aIdx1), *(const f32x4*)(Af + aIdx1 + 4));
  } else {
    const u16* Ab = (const u16*)Av;
    ra0 = *(const bf16x8*)(Ab + aIdx0);
    ra1 = *(const bf16x8*)(Ab + aIdx1);
  }
  rb0 = *(const bf16x8*)Bg0;
  rb1 = *(const bf16x8*)Bg1;
  rb2 = hasB3 ? *(const bf16x8*)Bg2 : (bf16x8){0,0,0,0,0,0,0,0};

  for (int kt = 0; kt < 20; ++kt) {
    __syncthreads();
    *(bf16x8*)&Asub[als0 * 8] = ra0;
    *(bf16x8*)&Asub[als1 * 8] = ra1;
    *(bf16x8*)&Bsub[bls0 * 8] = rb0;
    *(bf16x8*)&Bsub[bls1 * 8] = rb1;
    if (hasB3) *(bf16x8*)&Bsub[bls2 * 8] = rb2;
    __syncthreads();
    if (kt < 19) {
      const int k1 = (kt + 1) * 32;
      if (aF32) {
        const float* Af = (const float*)Av;
        ra0 = pack8(*(const f32x4*)(Af + aIdx0 + k1), *(const f32x4*)(Af + aIdx0 + k1 + 4));
        ra1 = pack8(*(const f32x4*)(Af + aIdx1 + k1), *(const f32x4*)(Af + aIdx1 + k1 + 4));
      } else {
        const u16* Ab = (const u16*)Av;
        ra0 = *(const bf16x8*)(Ab + aIdx0 + k1);
        ra1 = *(const bf16x8*)(Ab + aIdx1 + k1);
      }
      rb0 = *(const bf16x8*)(Bg0 + k1);
      rb1 = *(const bf16x8*)(Bg1 + k1);
      if (hasB3) rb2 = *(const bf16x8*)(Bg2 + k1);
    }
    bf16x8 a[4], b[5];
#pragma unroll
    for (int f = 0; f < 4; ++f) a[f] = *(const bf16x8*)&Asub[aoff[f]];
#pragma unroll
    for (int j = 0; j < 5; ++j) b[j] = *(const bf16x8*)&Bsub[boff[j]];
    __builtin_amdgcn_s_setprio(1);
#pragma unroll
    for (int i = 0; i < 4; ++i)
#pragma unroll
      for (int j = 0; j < 5; ++j)
        acc[i][j] = __builtin_amdgcn_mfma_f32_16x16x32_bf16(a[i], b[j], acc[i][j], 0, 0, 0);
    __builtin_amdgcn_s_setprio(0);
  }

#pragma unroll
  for (int j = 0; j < 5; ++j) {
    int col = colBase + wc * 80 + j * 16 + l15;
    float bb = 0.f;
    if (bias) bb = cF32 ? ((const float*)bias)[col] : b2f(((const u16*)bias)[col]);
#pragma unroll
    for (int i = 0; i < 4; ++i) {
      int row = rowBase + wr * 64 + i * 16 + g * 4;
#pragma unroll
      for (int r = 0; r < 4; ++r) {
        float v = acc[i][j][r] * scale + bb;
        if (cF32) ((float*)Cv)[(size_t)(row + r) * D640 + col] = v;
        else      ((u16*)Cv)[(size_t)(row + r) * D640 + col] = f2b(v);
      }
    }
  }
}

// ---------- gemm3: 128x128 bf16 GEMM via global_load_lds (out-proj; r12-proven) ------
__global__ __launch_bounds__(256) void gemm3(
    const u16* __restrict__ A, const u16* __restrict__ BT, void* __restrict__ Cv,
    float scale, const void* __restrict__ bias, const u32* __restrict__ flag,
    int aRow0, int cMode)
{
  __shared__ __align__(16) u16 Asub[128 * 32];
  __shared__ __align__(16) u16 Bsub[128 * 32];
  const bool isF32 = (*flag != 0);
  const bool cF32 = (cMode == 1) && isF32;
  const int tid = threadIdx.x;
  const int lane = tid & 63, w = tid >> 6;
  const int wr = w >> 1, wc = w & 1;
  const int l15 = lane & 15, g = lane >> 4;
  const int rowBase = blockIdx.x * 128;
  const int colBase = blockIdx.y * 128;

  const int c0 = w * 128 + lane, c1 = c0 + 64;
  const u16* Ag0 = A + (size_t)(aRow0 + rowBase + (c0 >> 2)) * D640 + ((c0 & 3) ^ ((c0 >> 3) & 3)) * 8;
  const u16* Ag1 = A + (size_t)(aRow0 + rowBase + (c1 >> 2)) * D640 + ((c1 & 3) ^ ((c1 >> 3) & 3)) * 8;
  const u16* Bg0 = BT + (size_t)(colBase + (c0 >> 2)) * D640 + ((c0 & 3) ^ ((c0 >> 3) & 3)) * 8;
  const u16* Bg1 = BT + (size_t)(colBase + (c1 >> 2)) * D640 + ((c1 & 3) ^ ((c1 >> 3) & 3)) * 8;
  u16* lA0 = &Asub[w * 1024];
  u16* lA1 = &Asub[w * 1024 + 512];
  u16* lB0 = &Bsub[w * 1024];
  u16* lB1 = &Bsub[w * 1024 + 512];

  int aoff[4], boff[4];
#pragma unroll
  for (int f = 0; f < 4; ++f) {
    int R = wr * 64 + f * 16 + l15;
    aoff[f] = (R * 4 + (g ^ ((R >> 1) & 3))) * 8;
    int Cc = wc * 64 + f * 16 + l15;
    boff[f] = (Cc * 4 + (g ^ ((Cc >> 1) & 3))) * 8;
  }

  f32x4 acc[4][4];
#pragma unroll
  for (int i = 0; i < 4; ++i)
#pragma unroll
    for (int j = 0; j < 4; ++j) acc[i][j] = (f32x4){0.f, 0.f, 0.f, 0.f};

  for (int kt = 0; kt < 20; ++kt) {
    __syncthreads();
    gld_lds16(Ag0 + kt * 32, lA0);
    gld_lds16(Ag1 + kt * 32, lA1);
    gld_lds16(Bg0 + kt * 32, lB0);
    gld_lds16(Bg1 + kt * 32, lB1);
    __syncthreads();
    bf16x8 a[4], b[4];
#pragma unroll
    for (int f = 0; f < 4; ++f) a[f] = *(const bf16x8*)&Asub[aoff[f]];
#pragma unroll
    for (int f = 0; f < 4; ++f) b[f] = *(const bf16x8*)&Bsub[boff[f]];
    __builtin_amdgcn_s_setprio(1);
#pragma unroll
    for (int i = 0; i < 4; ++i)
#pragma unroll
      for (int j = 0; j < 4; ++j)
        acc[i][j] = __builtin_amdgcn_mfma_f32_16x16x32_bf16(a[i], b[j], acc[i][j], 0, 0, 0);
    __builtin_amdgcn_s_setprio(0);
  }

#pragma unroll
  for (int j = 0; j < 4; ++j) {
    int col = colBase + wc * 64 + j * 16 + l15;
    float bb = 0.f;
    if (bias) bb = cF32 ? ((const float*)bias)[col] : b2f(((const u16*)bias)[col]);
#pragma unroll
    for (int i = 0; i < 4; ++i) {
      int row = rowBase + wr * 64 + i * 16 + g * 4;
#pragma unroll
      for (int r = 0; r < 4; ++r) {
        float v = acc[i][j][r] * scale + bb;
        if (cF32) ((float*)Cv)[(size_t)(row + r) * D640 + col] = v;
        else      ((u16*)Cv)[(size_t)(row + r) * D640 + col] = f2b(v);
      }
    }
  }
}

// ------------------- flash attention v7 (r12, unchanged: 89.2us) -------------------
__global__ __launch_bounds__(256, 3) void attn_kernel(
    const u16* __restrict__ Q, const u16* __restrict__ K2,
    const u16* __restrict__ VT, u16* __restrict__ AO)
{
  __shared__ __align__(16) u16 Klds[64 * 104];
  __shared__ __align__(16) u16 Vlds[80 * 72];

  const int tid = threadIdx.x, lane = tid & 63, w = tid >> 6;
  const int l15 = lane & 15, g = lane >> 4;
  const int qc = blockIdx.x, bh = blockIdx.y;
  const int f = bh >> 3, h = bh & 7;
  const int grp = f >> 3;

  const u16* Qp = Q + (size_t)(f * 1024 + qc * 128 + w * 32) * D640 + h * 80;
  const u16* Kp = K2 + (size_t)(grp * 1024) * D640 + h * 80;
  const u16* Vp = VT + (size_t)(grp * 8 + h) * 80 * 1024;

  if (tid < 128) {
    const bf16x8 z8 = {0, 0, 0, 0, 0, 0, 0, 0};
    *(bf16x8*)&Klds[(tid >> 1) * 104 + 80 + (tid & 1) * 8] = z8;
  }

  bf16x8 qreg[2][3];
#pragma unroll
  for (int qb = 0; qb < 2; ++qb)
#pragma unroll
    for (int dc = 0; dc < 3; ++dc) {
      int dd = dc * 32 + g * 8;
      if (dd < 80) qreg[qb][dc] = *(const bf16x8*)(Qp + (l15 + 16 * qb) * D640 + dd);
      else         qreg[qb][dc] = (bf16x8){0, 0, 0, 0, 0, 0, 0, 0};
    }

  f32x4 acc[2][5];
#pragma unroll
  for (int qb = 0; qb < 2; ++qb)
#pragma unroll
    for (int db = 0; db < 5; ++db) acc[qb][db] = (f32x4){0.f, 0.f, 0.f, 0.f};
  float mreg[2] = {0.f, 0.f};
  float lrow[2] = {0.f, 0.f};

  const u16* gsrc[5];
  u16* ldst[5];
  int step[5];
#pragma unroll
  for (int i = 0; i < 5; ++i) {
    int c = tid + i * 256;
    if (c < 640) {
      int row = c / 10, cc = c - row * 10;
      gsrc[i] = Kp + row * D640 + cc * 8;
      ldst[i] = &Klds[row * 104 + cc * 8];
      step[i] = 64 * D640;
    } else {
      int c2 = c - 640, d = c2 >> 3, cc = c2 & 7;
      gsrc[i] = Vp + d * 1024 + cc * 8;
      ldst[i] = &Vlds[d * 72 + cc * 8];
      step[i] = 64;
    }
  }

  bf16x8 pre[5];
#pragma unroll
  for (int i = 0; i < 5; ++i) pre[i] = *(const bf16x8*)gsrc[i];

  for (int it = 0; it < 16; ++it) {
    __syncthreads();
#pragma unroll
    for (int i = 0; i < 5; ++i) *(bf16x8*)ldst[i] = pre[i];
    __syncthreads();
    if (it < 15) {
#pragma unroll
      for (int i = 0; i < 5; ++i) pre[i] = *(const bf16x8*)(gsrc[i] + (it + 1) * step[i]);
    }

    f32x4 st[4][2];
#pragma unroll
    for (int kb = 0; kb < 4; ++kb)
#pragma unroll
      for (int qb = 0; qb < 2; ++qb) st[kb][qb] = (f32x4){0.f, 0.f, 0.f, 0.f};
    __builtin_amdgcn_s_setprio(1);
#pragma unroll
    for (int dc = 0; dc < 3; ++dc)
#pragma unroll
      for (int kb = 0; kb < 4; ++kb) {
        bf16x8 ka = *(const bf16x8*)&Klds[(kb * 16 + l15) * 104 + dc * 32 + g * 8];
        st[kb][0] = __builtin_amdgcn_mfma_f32_16x16x32_bf16(ka, qreg[0][dc], st[kb][0], 0, 0, 0);
        st[kb][1] = __builtin_amdgcn_mfma_f32_16x16x32_bf16(ka, qreg[1][dc], st[kb][1], 0, 0, 0);
      }
    __builtin_amdgcn_s_setprio(0);

    float mt[2];
#pragma unroll
    for (int qb = 0; qb < 2; ++qb) {
      float m01 = fmaxf(fmaxf(st[0][qb][0], st[0][qb][1]), fmaxf(st[0][qb][2], st[0][qb][3]));
      float m23 = fmaxf(fmaxf(st[1][qb][0], st[1][qb][1]), fmaxf(st[1][qb][2], st[1][qb][3]));
      float m45 = fmaxf(fmaxf(st[2][qb][0], st[2][qb][1]), fmaxf(st[2][qb][2], st[2][qb][3]));
      float m67 = fmaxf(fmaxf(st[3][qb][0], st[3][qb][1]), fmaxf(st[3][qb][2], st[3][qb][3]));
      mt[qb] = fmaxf(fmaxf(m01, m23), fmaxf(m45, m67));
    }

    if (__any((mt[0] > mreg[0] + 8.f) || (mt[1] > mreg[1] + 8.f))) {
#pragma unroll
      for (int qb = 0; qb < 2; ++qb) {
        float m = mt[qb];
        m = fmaxf(m, __shfl_xor(m, 16, 64));
        m = fmaxf(m, __shfl_xor(m, 32, 64));
        float mn = fmaxf(mreg[qb], m);
        float scl = exp2f(mreg[qb] - mn);
        mreg[qb] = mn;
        lrow[qb] *= scl;
        float s_[4];
#pragma unroll
        for (int r = 0; r < 4; ++r)
          s_[r] = __shfl(scl, (lane & 48) | (g * 4 + r), 64);
#pragma unroll
        for (int db = 0; db < 5; ++db)
#pragma unroll
          for (int r = 0; r < 4; ++r) acc[qb][db][r] *= s_[r];
      }
    }

    bf16x8 pa[2][2];
#pragma unroll
    for (int qb = 0; qb < 2; ++qb) {
      float sum = 0.f;
      u32 wlo[4], whi[4];
#pragma unroll
      for (int kb = 0; kb < 4; ++kb) {
        float p0 = exp2f(st[kb][qb][0] - mreg[qb]);
        float p1 = exp2f(st[kb][qb][1] - mreg[qb]);
        float p2 = exp2f(st[kb][qb][2] - mreg[qb]);
        float p3 = exp2f(st[kb][qb][3] - mreg[qb]);
        sum += (p0 + p1) + (p2 + p3);
        wlo[kb] = pack2(p0, p1);
        whi[kb] = pack2(p2, p3);
      }
      lrow[qb] += sum;
#pragma unroll
      for (int kc = 0; kc < 2; ++kc) {
        union { u32 u[4]; bf16x8 v; } cvt;
        cvt.u[0] = wlo[2 * kc];
        cvt.u[1] = whi[2 * kc];
        cvt.u[2] = wlo[2 * kc + 1];
        cvt.u[3] = whi[2 * kc + 1];
        pa[qb][kc] = cvt.v;
      }
    }

    __builtin_amdgcn_s_setprio(1);
#pragma unroll
    for (int kc = 0; kc < 2; ++kc) {
#pragma unroll
      for (int db = 0; db < 5; ++db) {
        bf16x8 bv = *(const bf16x8*)&Vlds[(db * 16 + l15) * 72 + kc * 32 + g * 8];
        acc[0][db] = __builtin_amdgcn_mfma_f32_16x16x32_bf16(pa[0][kc], bv, acc[0][db], 0, 0, 0);
        acc[1][db] = __builtin_amdgcn_mfma_f32_16x16x32_bf16(pa[1][kc], bv, acc[1][db], 0, 0, 0);
      }
    }
    __builtin_amdgcn_s_setprio(0);
  }

  u16* Op = AO + (size_t)(f * 1024 + qc * 128 + w * 32) * D640 + h * 80;
#pragma unroll
  for (int qb = 0; qb < 2; ++qb) {
    float lr = lrow[qb];
    lr += __shfl_xor(lr, 16, 64);
    lr += __shfl_xor(lr, 32, 64);
    float i_[4];
#pragma unroll
    for (int r = 0; r < 4; ++r)
      i_[r] = 1.f / __shfl(lr, (lane & 48) | (g * 4 + r), 64);
#pragma unroll
    for (int db = 0; db < 5; ++db)
#pragma unroll
      for (int r = 0; r < 4; ++r)
        Op[(qb * 16 + g * 4 + r) * D640 + db * 16 + l15] = f2b(acc[qb][db][r] * i_[r]);
  }
}

// ------------------- launcher -------------------
extern "C" void kernel_launch(void* const* d_in, const int* in_sizes, int n_in,
                              void* d_out, int out_size, void* d_ws, size_t ws_size,
                              hipStream_t stream) {
  (void)in_sizes; (void)n_in; (void)out_size; (void)ws_size;
  const void* hs = d_in[0];
  const void* wq = d_in[1];
  const void* wk = d_in[2];
  const void* wv = d_in[3];
  const void* wo = d_in[4];
  const void* bo = d_in[5];
  u16* ws = (u16*)d_ws;

  u16* WT  = ws;                         // 4 * 640*640           bf16
  u16* Qb  = ws + 1638400;               // 16384*640             bf16
  u16* Kb  = Qb + 10485760;              // 2048*640              bf16
  u16* Vb  = Kb + 1310720;               // V^T key-permuted: 2 grp x [640][1024]
  u16* AOb = Vb + 1310720;               // 16384*640             bf16
  u32* flag = (u32*)(AOb + 10485760);    // dtype flag

  const float QSCALE = 0.11180339887498949f * 1.44269504088896340f;

  detect_dtype<<<1, 256, 0, stream>>>((const u16*)hs, flag);
  transpose_w<<<dim3(20, 20, 4), dim3(32, 8), 0, stream>>>(wq, wk, wv, wo, WT, flag);

  // Q projection (scale folded): r10-proven gemm2 BM=128/BN=160, 512 blocks
  gemm2<<<dim3(128, 4), 256, 0, stream>>>(hs, WT, Qb, QSCALE, nullptr, flag, 1, 0);
  // K and V (V transposed + key-permuted): r11-proven reg-staged body
  gemm_kv<<<dim3(8, 5, 4), 256, 0, stream>>>(hs, WT + 409600, WT + 819200, Kb, Vb, flag);

  attn_kernel<<<dim3(8, 128), 256, 0, stream>>>(Qb, Kb, Vb, AOb);

  // output projection + bias (bf16 A -> gload_lds is a pure win here)
  gemm3<<<dim3(128, 5), 256, 0, stream>>>(AOb, WT + 1228800, d_out, 1.f, bo, flag, 0, 1);
}

// Round 16
// 163.370 us; speedup vs baseline: 1.1086x; 1.0057x over previous
//
#include <hip/hip_runtime.h>
#include <hip/hip_bf16.h>

typedef unsigned short u16;
typedef unsigned int u32;
typedef __attribute__((ext_vector_type(8))) short bf16x8;
typedef __attribute__((ext_vector_type(4))) float f32x4;

#define D640 640

__device__ __forceinline__ float b2f(u16 u) {
  union { u32 i; float f; } x; x.i = ((u32)u) << 16; return x.f;
}
__device__ __forceinline__ u16 f2b(float f) {
  union { __hip_bfloat16 h; u16 u; } c; c.h = __float2bfloat16(f); return c.u;
}
__device__ __forceinline__ u32 pack2(float a, float b) {
  union { __hip_bfloat162 h; u32 u; } c;
  c.h.x = __float2bfloat16(a); c.h.y = __float2bfloat16(b); return c.u;
}
__device__ __forceinline__ bf16x8 pack8(f32x4 lo, f32x4 hi) {
  bf16x8 r;
  r[0] = (short)f2b(lo[0]); r[1] = (short)f2b(lo[1]);
  r[2] = (short)f2b(lo[2]); r[3] = (short)f2b(lo[3]);
  r[4] = (short)f2b(hi[0]); r[5] = (short)f2b(hi[1]);
  r[6] = (short)f2b(hi[2]); r[7] = (short)f2b(hi[3]);
  return r;
}
__device__ __forceinline__ void gld_lds16(const u16* g, u16* l) {
  __builtin_amdgcn_global_load_lds((const __attribute__((address_space(1))) u32*)g,
                                   (__attribute__((address_space(3))) u32*)l, 16, 0, 0);
}

// ------------- dtype detector: inputs bf16 (flag=0) or fp32 (flag=1)? -------------
__global__ void detect_dtype(const u16* __restrict__ hs, u32* __restrict__ flag) {
  __shared__ u32 cnt;
  if (threadIdx.x == 0) cnt = 0;
  __syncthreads();
  int plaus = 0;
#pragma unroll
  for (int i = 0; i < 16; ++i) {
    u16 u = hs[(threadIdx.x * 16 + i) * 2];
    u32 e = (u >> 7) & 0xFF;
    if ((e >= 0x70 && e <= 0x8F) || (u & 0x7FFF) == 0) plaus++;
  }
  atomicAdd(&cnt, (u32)plaus);
  __syncthreads();
  if (threadIdx.x == 0) *flag = (cnt < 2048) ? 1u : 0u;
}

// ------------------- transpose (+convert) the 4 weight matrices -> bf16 -------------------
__global__ __launch_bounds__(256) void transpose_w(
    const void* __restrict__ w0, const void* __restrict__ w1,
    const void* __restrict__ w2, const void* __restrict__ w3,
    u16* __restrict__ out, const u32* __restrict__ flag)
{
  __shared__ u16 t[32][33];
  const bool isF32 = (*flag != 0);
  const void* src = blockIdx.z == 0 ? w0 : blockIdx.z == 1 ? w1 : blockIdx.z == 2 ? w2 : w3;
  u16* dst = out + (size_t)blockIdx.z * 409600;
  int tx = threadIdx.x, ty = threadIdx.y;
  int x = blockIdx.x * 32 + tx;
  int y = blockIdx.y * 32 + ty;
  if (isF32) {
    const float* s = (const float*)src;
#pragma unroll
    for (int j = 0; j < 32; j += 8) t[ty + j][tx] = f2b(s[(y + j) * D640 + x]);
  } else {
    const u16* s = (const u16*)src;
#pragma unroll
    for (int j = 0; j < 32; j += 8) t[ty + j][tx] = s[(y + j) * D640 + x];
  }
  __syncthreads();
  int x2 = blockIdx.y * 32 + tx;
  int y2 = blockIdx.x * 32 + ty;
#pragma unroll
  for (int j = 0; j < 32; j += 8) dst[(y2 + j) * D640 + x2] = t[tx][ty + j];
}

// ------------------- 128x128-tile bf16 GEMM body (K/V projections; r11-proven) ----------
// cMode: 0 bf16 [row][640];
//        2 bf16 V^T KEY-PERMUTED: slot (k&32)|((k&12)<<1)|(((k>>4)&1)<<2)|(k&3)
__device__ __forceinline__ void gemm_body(
    const void* __restrict__ Av, const u16* __restrict__ BT, void* __restrict__ Cv,
    float scale, bool isF32, int aRow0, int cMode, int bx, int by)
{
  __shared__ __align__(16) u16 Asub[128 * 32];
  __shared__ __align__(16) u16 Bsub[128 * 32];
  const bool aF32 = isF32;
  const int tid = threadIdx.x;
  const int lane = tid & 63, w = tid >> 6;
  const int wr = w >> 1, wc = w & 1;
  const int l15 = lane & 15, g = lane >> 4;
  const int rowBase = bx * 128;
  const int colBase = by * 128;

  const int r0 = tid >> 2, r1 = r0 + 64, gc = tid & 3;
  const int ls0 = r0 * 4 + (gc ^ ((r0 >> 1) & 3));
  const int ls1 = r1 * 4 + (gc ^ ((r1 >> 1) & 3));
  const size_t aIdx0 = (size_t)(aRow0 + rowBase + r0) * D640 + gc * 8;
  const size_t aIdx1 = (size_t)(aRow0 + rowBase + r1) * D640 + gc * 8;
  const u16* Bg0 = BT + (colBase + r0) * D640 + gc * 8;
  const u16* Bg1 = BT + (colBase + r1) * D640 + gc * 8;

  int aoff[4], boff[4];
#pragma unroll
  for (int f = 0; f < 4; ++f) {
    int R = wr * 64 + f * 16 + l15;
    aoff[f] = (R * 4 + (g ^ ((R >> 1) & 3))) * 8;
    int Cc = wc * 64 + f * 16 + l15;
    boff[f] = (Cc * 4 + (g ^ ((Cc >> 1) & 3))) * 8;
  }

  f32x4 acc[4][4];
#pragma unroll
  for (int i = 0; i < 4; ++i)
#pragma unroll
    for (int j = 0; j < 4; ++j) acc[i][j] = (f32x4){0.f, 0.f, 0.f, 0.f};

  bf16x8 ra0, ra1, rb0, rb1;
  if (aF32) {
    const float* Af = (const float*)Av;
    ra0 = pack8(*(const f32x4*)(Af + aIdx0), *(const f32x4*)(Af + aIdx0 + 4));
    ra1 = pack8(*(const f32x4*)(Af + aIdx1), *(const f32x4*)(Af + aIdx1 + 4));
  } else {
    const u16* Ab = (const u16*)Av;
    ra0 = *(const bf16x8*)(Ab + aIdx0);
    ra1 = *(const bf16x8*)(Ab + aIdx1);
  }
  rb0 = *(const bf16x8*)Bg0;
  rb1 = *(const bf16x8*)Bg1;

  for (int kt = 0; kt < 20; ++kt) {
    __syncthreads();
    *(bf16x8*)&Asub[ls0 * 8] = ra0;
    *(bf16x8*)&Asub[ls1 * 8] = ra1;
    *(bf16x8*)&Bsub[ls0 * 8] = rb0;
    *(bf16x8*)&Bsub[ls1 * 8] = rb1;
    __syncthreads();
    if (kt < 19) {
      const int k1 = (kt + 1) * 32;
      if (aF32) {
        const float* Af = (const float*)Av;
        ra0 = pack8(*(const f32x4*)(Af + aIdx0 + k1), *(const f32x4*)(Af + aIdx0 + k1 + 4));
        ra1 = pack8(*(const f32x4*)(Af + aIdx1 + k1), *(const f32x4*)(Af + aIdx1 + k1 + 4));
      } else {
        const u16* Ab = (const u16*)Av;
        ra0 = *(const bf16x8*)(Ab + aIdx0 + k1);
        ra1 = *(const bf16x8*)(Ab + aIdx1 + k1);
      }
      rb0 = *(const bf16x8*)(Bg0 + k1);
      rb1 = *(const bf16x8*)(Bg1 + k1);
    }
    bf16x8 a[4], b[4];
#pragma unroll
    for (int f = 0; f < 4; ++f) a[f] = *(const bf16x8*)&Asub[aoff[f]];
#pragma unroll
    for (int f = 0; f < 4; ++f) b[f] = *(const bf16x8*)&Bsub[boff[f]];
    __builtin_amdgcn_s_setprio(1);
#pragma unroll
    for (int i = 0; i < 4; ++i)
#pragma unroll
      for (int j = 0; j < 4; ++j)
        acc[i][j] = __builtin_amdgcn_mfma_f32_16x16x32_bf16(a[i], b[j], acc[i][j], 0, 0, 0);
    __builtin_amdgcn_s_setprio(0);
  }

#pragma unroll
  for (int j = 0; j < 4; ++j) {
    int col = colBase + wc * 64 + j * 16 + l15;
#pragma unroll
    for (int i = 0; i < 4; ++i) {
      int row = rowBase + wr * 64 + i * 16 + g * 4;
#pragma unroll
      for (int r = 0; r < 4; ++r) {
        float v = acc[i][j][r] * scale;
        if (cMode == 2) {
          int rw = row + r;
          int rl = rw & 63;
          int slot = (rl & 32) | ((rl & 12) << 1) | (((rl >> 4) & 1) << 2) | (rl & 3);
          ((u16*)Cv)[(size_t)col * 1024 + (rw & ~63) + slot] = f2b(v);
        } else {
          ((u16*)Cv)[(size_t)(row + r) * D640 + col] = f2b(v);
        }
      }
    }
  }
}

// merged K/V projection: z = 0: K grp0, 1: K grp1, 2: V grp0 (perm V^T), 3: V grp1
__global__ __launch_bounds__(256) void gemm_kv(
    const void* __restrict__ hs, const u16* __restrict__ WTk, const u16* __restrict__ WTv,
    u16* __restrict__ Kb, u16* __restrict__ Vb, const u32* __restrict__ flag)
{
  const int z = blockIdx.z;
  const bool isK = (z < 2);
  const int grp = z & 1;
  const u16* bt = isK ? WTk : WTv;
  void* cv = isK ? (void*)(Kb + (size_t)grp * 655360)
                 : (void*)(Vb + (size_t)grp * 655360);
  gemm_body(hs, bt, cv, 1.f, (*flag != 0), grp * 8192, isK ? 0 : 2,
            blockIdx.x, blockIdx.y);
}

// -------- gemm2q: BM=64, BN=160 Q-projection GEMM. grid (256,4) = 1024 blocks = 4/CU.
// Theory: r15's gemm2 at 512 blocks = 2 waves/SIMD is TLP-starved (barrier chain
// exposed). Halve BM -> 2x blocks -> 16 waves/CU. Trade: 10 MFMA/barrier-pair vs 20.
// A: fp32 reg-staged 1 chunk/thread; B: bf16 reg-staged 2-3 chunks (wave-uniform 3rd).
__global__ __launch_bounds__(256) void gemm2q(
    const void* __restrict__ Av, const u16* __restrict__ BT, u16* __restrict__ Cv,
    float scale, const u32* __restrict__ flag)
{
  __shared__ __align__(16) u16 Asub[64 * 32];
  __shared__ __align__(16) u16 Bsub[160 * 32];
  const bool aF32 = (*flag != 0);
  const int tid = threadIdx.x;
  const int lane = tid & 63, w = tid >> 6;
  const int wr = w >> 1, wc = w & 1;
  const int l15 = lane & 15, g = lane >> 4;
  const int rowBase = blockIdx.x * 64;
  const int colBase = blockIdx.y * 160;

  // A staging: 256 chunks, 1/thread
  const int ar0 = tid >> 2, gc = tid & 3;
  const int als0 = ar0 * 4 + (gc ^ ((ar0 >> 1) & 3));
  const size_t aIdx0 = (size_t)(rowBase + ar0) * D640 + gc * 8;
  // B staging: 640 chunks, 2/thread + 1 extra for tid<128 (wave-uniform halves)
  const bool hasB3 = (tid < 128);
  const int br0 = tid >> 2, br1 = br0 + 64, br2 = hasB3 ? (128 + (tid >> 2)) : 0;
  const int bls0 = br0 * 4 + (gc ^ ((br0 >> 1) & 3));
  const int bls1 = br1 * 4 + (gc ^ ((br1 >> 1) & 3));
  const int bls2 = br2 * 4 + (gc ^ ((br2 >> 1) & 3));
  const u16* Bg0 = BT + (colBase + br0) * D640 + gc * 8;
  const u16* Bg1 = BT + (colBase + br1) * D640 + gc * 8;
  const u16* Bg2 = BT + (colBase + br2) * D640 + gc * 8;

  int aoff[2], boff[5];
#pragma unroll
  for (int f = 0; f < 2; ++f) {
    int R = wr * 32 + f * 16 + l15;
    aoff[f] = (R * 4 + (g ^ ((R >> 1) & 3))) * 8;
  }
#pragma unroll
  for (int j = 0; j < 5; ++j) {
    int Cc = wc * 80 + j * 16 + l15;
    boff[j] = (Cc * 4 + (g ^ ((Cc >> 1) & 3))) * 8;
  }

  f32x4 acc[2][5];
#pragma unroll
  for (int i = 0; i < 2; ++i)
#pragma unroll
    for (int j = 0; j < 5; ++j) acc[i][j] = (f32x4){0.f, 0.f, 0.f, 0.f};

  bf16x8 ra0, rb0, rb1, rb2;
  if (aF32) {
    const float* Af = (const float*)Av;
    ra0 = pack8(*(const f32x4*)(Af + aIdx0), *(const f32x4*)(Af + aIdx0 + 4));
  } else {
    const u16* Ab = (const u16*)Av;
    ra0 = *(const bf16x8*)(Ab + aIdx0);
  }
  rb0 = *(const bf16x8*)Bg0;
  rb1 = *(const bf16x8*)Bg1;
  rb2 = hasB3 ? *(const bf16x8*)Bg2 : (bf16x8){0,0,0,0,0,0,0,0};

  for (int kt = 0; kt < 20; ++kt) {
    __syncthreads();
    *(bf16x8*)&Asub[als0 * 8] = ra0;
    *(bf16x8*)&Bsub[bls0 * 8] = rb0;
    *(bf16x8*)&Bsub[bls1 * 8] = rb1;
    if (hasB3) *(bf16x8*)&Bsub[bls2 * 8] = rb2;
    __syncthreads();
    if (kt < 19) {
      const int k1 = (kt + 1) * 32;
      if (aF32) {
        const float* Af = (const float*)Av;
        ra0 = pack8(*(const f32x4*)(Af + aIdx0 + k1), *(const f32x4*)(Af + aIdx0 + k1 + 4));
      } else {
        const u16* Ab = (const u16*)Av;
        ra0 = *(const bf16x8*)(Ab + aIdx0 + k1);
      }
      rb0 = *(const bf16x8*)(Bg0 + k1);
      rb1 = *(const bf16x8*)(Bg1 + k1);
      if (hasB3) rb2 = *(const bf16x8*)(Bg2 + k1);
    }
    bf16x8 a[2], b[5];
#pragma unroll
    for (int f = 0; f < 2; ++f) a[f] = *(const bf16x8*)&Asub[aoff[f]];
#pragma unroll
    for (int j = 0; j < 5; ++j) b[j] = *(const bf16x8*)&Bsub[boff[j]];
    __builtin_amdgcn_s_setprio(1);
#pragma unroll
    for (int i = 0; i < 2; ++i)
#pragma unroll
      for (int j = 0; j < 5; ++j)
        acc[i][j] = __builtin_amdgcn_mfma_f32_16x16x32_bf16(a[i], b[j], acc[i][j], 0, 0, 0);
    __builtin_amdgcn_s_setprio(0);
  }

#pragma unroll
  for (int j = 0; j < 5; ++j) {
    int col = colBase + wc * 80 + j * 16 + l15;
#pragma unroll
    for (int i = 0; i < 2; ++i) {
      int row = rowBase + wr * 32 + i * 16 + g * 4;
#pragma unroll
      for (int r = 0; r < 4; ++r)
        Cv[(size_t)(row + r) * D640 + col] = f2b(acc[i][j][r] * scale);
    }
  }
}

// ---------- gemm3: 128x128 bf16 GEMM via global_load_lds (out-proj; r12-proven) ------
__global__ __launch_bounds__(256) void gemm3(
    const u16* __restrict__ A, const u16* __restrict__ BT, void* __restrict__ Cv,
    float scale, const void* __restrict__ bias, const u32* __restrict__ flag,
    int aRow0, int cMode)
{
  __shared__ __align__(16) u16 Asub[128 * 32];
  __shared__ __align__(16) u16 Bsub[128 * 32];
  const bool isF32 = (*flag != 0);
  const bool cF32 = (cMode == 1) && isF32;
  const int tid = threadIdx.x;
  const int lane = tid & 63, w = tid >> 6;
  const int wr = w >> 1, wc = w & 1;
  const int l15 = lane & 15, g = lane >> 4;
  const int rowBase = blockIdx.x * 128;
  const int colBase = blockIdx.y * 128;

  const int c0 = w * 128 + lane, c1 = c0 + 64;
  const u16* Ag0 = A + (size_t)(aRow0 + rowBase + (c0 >> 2)) * D640 + ((c0 & 3) ^ ((c0 >> 3) & 3)) * 8;
  const u16* Ag1 = A + (size_t)(aRow0 + rowBase + (c1 >> 2)) * D640 + ((c1 & 3) ^ ((c1 >> 3) & 3)) * 8;
  const u16* Bg0 = BT + (size_t)(colBase + (c0 >> 2)) * D640 + ((c0 & 3) ^ ((c0 >> 3) & 3)) * 8;
  const u16* Bg1 = BT + (size_t)(colBase + (c1 >> 2)) * D640 + ((c1 & 3) ^ ((c1 >> 3) & 3)) * 8;
  u16* lA0 = &Asub[w * 1024];
  u16* lA1 = &Asub[w * 1024 + 512];
  u16* lB0 = &Bsub[w * 1024];
  u16* lB1 = &Bsub[w * 1024 + 512];

  int aoff[4], boff[4];
#pragma unroll
  for (int f = 0; f < 4; ++f) {
    int R = wr * 64 + f * 16 + l15;
    aoff[f] = (R * 4 + (g ^ ((R >> 1) & 3))) * 8;
    int Cc = wc * 64 + f * 16 + l15;
    boff[f] = (Cc * 4 + (g ^ ((Cc >> 1) & 3))) * 8;
  }

  f32x4 acc[4][4];
#pragma unroll
  for (int i = 0; i < 4; ++i)
#pragma unroll
    for (int j = 0; j < 4; ++j) acc[i][j] = (f32x4){0.f, 0.f, 0.f, 0.f};

  for (int kt = 0; kt < 20; ++kt) {
    __syncthreads();
    gld_lds16(Ag0 + kt * 32, lA0);
    gld_lds16(Ag1 + kt * 32, lA1);
    gld_lds16(Bg0 + kt * 32, lB0);
    gld_lds16(Bg1 + kt * 32, lB1);
    __syncthreads();
    bf16x8 a[4], b[4];
#pragma unroll
    for (int f = 0; f < 4; ++f) a[f] = *(const bf16x8*)&Asub[aoff[f]];
#pragma unroll
    for (int f = 0; f < 4; ++f) b[f] = *(const bf16x8*)&Bsub[boff[f]];
    __builtin_amdgcn_s_setprio(1);
#pragma unroll
    for (int i = 0; i < 4; ++i)
#pragma unroll
      for (int j = 0; j < 4; ++j)
        acc[i][j] = __builtin_amdgcn_mfma_f32_16x16x32_bf16(a[i], b[j], acc[i][j], 0, 0, 0);
    __builtin_amdgcn_s_setprio(0);
  }

#pragma unroll
  for (int j = 0; j < 4; ++j) {
    int col = colBase + wc * 64 + j * 16 + l15;
    float bb = 0.f;
    if (bias) bb = cF32 ? ((const float*)bias)[col] : b2f(((const u16*)bias)[col]);
#pragma unroll
    for (int i = 0; i < 4; ++i) {
      int row = rowBase + wr * 64 + i * 16 + g * 4;
#pragma unroll
      for (int r = 0; r < 4; ++r) {
        float v = acc[i][j][r] * scale + bb;
        if (cF32) ((float*)Cv)[(size_t)(row + r) * D640 + col] = v;
        else      ((u16*)Cv)[(size_t)(row + r) * D640 + col] = f2b(v);
      }
    }
  }
}

// ------------------- flash attention v7 (r12, unchanged: 89.2us) -------------------
__global__ __launch_bounds__(256, 3) void attn_kernel(
    const u16* __restrict__ Q, const u16* __restrict__ K2,
    const u16* __restrict__ VT, u16* __restrict__ AO)
{
  __shared__ __align__(16) u16 Klds[64 * 104];
  __shared__ __align__(16) u16 Vlds[80 * 72];

  const int tid = threadIdx.x, lane = tid & 63, w = tid >> 6;
  const int l15 = lane & 15, g = lane >> 4;
  const int qc = blockIdx.x, bh = blockIdx.y;
  const int f = bh >> 3, h = bh & 7;
  const int grp = f >> 3;

  const u16* Qp = Q + (size_t)(f * 1024 + qc * 128 + w * 32) * D640 + h * 80;
  const u16* Kp = K2 + (size_t)(grp * 1024) * D640 + h * 80;
  const u16* Vp = VT + (size_t)(grp * 8 + h) * 80 * 1024;

  if (tid < 128) {
    const bf16x8 z8 = {0, 0, 0, 0, 0, 0, 0, 0};
    *(bf16x8*)&Klds[(tid >> 1) * 104 + 80 + (tid & 1) * 8] = z8;
  }

  bf16x8 qreg[2][3];
#pragma unroll
  for (int qb = 0; qb < 2; ++qb)
#pragma unroll
    for (int dc = 0; dc < 3; ++dc) {
      int dd = dc * 32 + g * 8;
      if (dd < 80) qreg[qb][dc] = *(const bf16x8*)(Qp + (l15 + 16 * qb) * D640 + dd);
      else         qreg[qb][dc] = (bf16x8){0, 0, 0, 0, 0, 0, 0, 0};
    }

  f32x4 acc[2][5];
#pragma unroll
  for (int qb = 0; qb < 2; ++qb)
#pragma unroll
    for (int db = 0; db < 5; ++db) acc[qb][db] = (f32x4){0.f, 0.f, 0.f, 0.f};
  float mreg[2] = {0.f, 0.f};
  float lrow[2] = {0.f, 0.f};

  const u16* gsrc[5];
  u16* ldst[5];
  int step[5];
#pragma unroll
  for (int i = 0; i < 5; ++i) {
    int c = tid + i * 256;
    if (c < 640) {
      int row = c / 10, cc = c - row * 10;
      gsrc[i] = Kp + row * D640 + cc * 8;
      ldst[i] = &Klds[row * 104 + cc * 8];
      step[i] = 64 * D640;
    } else {
      int c2 = c - 640, d = c2 >> 3, cc = c2 & 7;
      gsrc[i] = Vp + d * 1024 + cc * 8;
      ldst[i] = &Vlds[d * 72 + cc * 8];
      step[i] = 64;
    }
  }

  bf16x8 pre[5];
#pragma unroll
  for (int i = 0; i < 5; ++i) pre[i] = *(const bf16x8*)gsrc[i];

  for (int it = 0; it < 16; ++it) {
    __syncthreads();
#pragma unroll
    for (int i = 0; i < 5; ++i) *(bf16x8*)ldst[i] = pre[i];
    __syncthreads();
    if (it < 15) {
#pragma unroll
      for (int i = 0; i < 5; ++i) pre[i] = *(const bf16x8*)(gsrc[i] + (it + 1) * step[i]);
    }

    f32x4 st[4][2];
#pragma unroll
    for (int kb = 0; kb < 4; ++kb)
#pragma unroll
      for (int qb = 0; qb < 2; ++qb) st[kb][qb] = (f32x4){0.f, 0.f, 0.f, 0.f};
    __builtin_amdgcn_s_setprio(1);
#pragma unroll
    for (int dc = 0; dc < 3; ++dc)
#pragma unroll
      for (int kb = 0; kb < 4; ++kb) {
        bf16x8 ka = *(const bf16x8*)&Klds[(kb * 16 + l15) * 104 + dc * 32 + g * 8];
        st[kb][0] = __builtin_amdgcn_mfma_f32_16x16x32_bf16(ka, qreg[0][dc], st[kb][0], 0, 0, 0);
        st[kb][1] = __builtin_amdgcn_mfma_f32_16x16x32_bf16(ka, qreg[1][dc], st[kb][1], 0, 0, 0);
      }
    __builtin_amdgcn_s_setprio(0);

    float mt[2];
#pragma unroll
    for (int qb = 0; qb < 2; ++qb) {
      float m01 = fmaxf(fmaxf(st[0][qb][0], st[0][qb][1]), fmaxf(st[0][qb][2], st[0][qb][3]));
      float m23 = fmaxf(fmaxf(st[1][qb][0], st[1][qb][1]), fmaxf(st[1][qb][2], st[1][qb][3]));
      float m45 = fmaxf(fmaxf(st[2][qb][0], st[2][qb][1]), fmaxf(st[2][qb][2], st[2][qb][3]));
      float m67 = fmaxf(fmaxf(st[3][qb][0], st[3][qb][1]), fmaxf(st[3][qb][2], st[3][qb][3]));
      mt[qb] = fmaxf(fmaxf(m01, m23), fmaxf(m45, m67));
    }

    if (__any((mt[0] > mreg[0] + 8.f) || (mt[1] > mreg[1] + 8.f))) {
#pragma unroll
      for (int qb = 0; qb < 2; ++qb) {
        float m = mt[qb];
        m = fmaxf(m, __shfl_xor(m, 16, 64));
        m = fmaxf(m, __shfl_xor(m, 32, 64));
        float mn = fmaxf(mreg[qb], m);
        float scl = exp2f(mreg[qb] - mn);
        mreg[qb] = mn;
        lrow[qb] *= scl;
        float s_[4];
#pragma unroll
        for (int r = 0; r < 4; ++r)
          s_[r] = __shfl(scl, (lane & 48) | (g * 4 + r), 64);
#pragma unroll
        for (int db = 0; db < 5; ++db)
#pragma unroll
          for (int r = 0; r < 4; ++r) acc[qb][db][r] *= s_[r];
      }
    }

    bf16x8 pa[2][2];
#pragma unroll
    for (int qb = 0; qb < 2; ++qb) {
      float sum = 0.f;
      u32 wlo[4], whi[4];
#pragma unroll
      for (int kb = 0; kb < 4; ++kb) {
        float p0 = exp2f(st[kb][qb][0] - mreg[qb]);
        float p1 = exp2f(st[kb][qb][1] - mreg[qb]);
        float p2 = exp2f(st[kb][qb][2] - mreg[qb]);
        float p3 = exp2f(st[kb][qb][3] - mreg[qb]);
        sum += (p0 + p1) + (p2 + p3);
        wlo[kb] = pack2(p0, p1);
        whi[kb] = pack2(p2, p3);
      }
      lrow[qb] += sum;
#pragma unroll
      for (int kc = 0; kc < 2; ++kc) {
        union { u32 u[4]; bf16x8 v; } cvt;
        cvt.u[0] = wlo[2 * kc];
        cvt.u[1] = whi[2 * kc];
        cvt.u[2] = wlo[2 * kc + 1];
        cvt.u[3] = whi[2 * kc + 1];
        pa[qb][kc] = cvt.v;
      }
    }

    __builtin_amdgcn_s_setprio(1);
#pragma unroll
    for (int kc = 0; kc < 2; ++kc) {
#pragma unroll
      for (int db = 0; db < 5; ++db) {
        bf16x8 bv = *(const bf16x8*)&Vlds[(db * 16 + l15) * 72 + kc * 32 + g * 8];
        acc[0][db] = __builtin_amdgcn_mfma_f32_16x16x32_bf16(pa[0][kc], bv, acc[0][db], 0, 0, 0);
        acc[1][db] = __builtin_amdgcn_mfma_f32_16x16x32_bf16(pa[1][kc], bv, acc[1][db], 0, 0, 0);
      }
    }
    __builtin_amdgcn_s_setprio(0);
  }

  u16* Op = AO + (size_t)(f * 1024 + qc * 128 + w * 32) * D640 + h * 80;
#pragma unroll
  for (int qb = 0; qb < 2; ++qb) {
    float lr = lrow[qb];
    lr += __shfl_xor(lr, 16, 64);
    lr += __shfl_xor(lr, 32, 64);
    float i_[4];
#pragma unroll
    for (int r = 0; r < 4; ++r)
      i_[r] = 1.f / __shfl(lr, (lane & 48) | (g * 4 + r), 64);
#pragma unroll
    for (int db = 0; db < 5; ++db)
#pragma unroll
      for (int r = 0; r < 4; ++r)
        Op[(qb * 16 + g * 4 + r) * D640 + db * 16 + l15] = f2b(acc[qb][db][r] * i_[r]);
  }
}

// ------------------- launcher -------------------
extern "C" void kernel_launch(void* const* d_in, const int* in_sizes, int n_in,
                              void* d_out, int out_size, void* d_ws, size_t ws_size,
                              hipStream_t stream) {
  (void)in_sizes; (void)n_in; (void)out_size; (void)ws_size;
  const void* hs = d_in[0];
  const void* wq = d_in[1];
  const void* wk = d_in[2];
  const void* wv = d_in[3];
  const void* wo = d_in[4];
  const void* bo = d_in[5];
  u16* ws = (u16*)d_ws;

  u16* WT  = ws;                         // 4 * 640*640           bf16
  u16* Qb  = ws + 1638400;               // 16384*640             bf16
  u16* Kb  = Qb + 10485760;               // 2048*640              bf16
  u16* Vb  = Kb + 1310720;               // V^T key-permuted: 2 grp x [640][1024]
  u16* AOb = Vb + 1310720;               // 16384*640             bf16
  u32* flag = (u32*)(AOb + 10485760);    // dtype flag

  const float QSCALE = 0.11180339887498949f * 1.44269504088896340f;

  detect_dtype<<<1, 256, 0, stream>>>((const u16*)hs, flag);
  transpose_w<<<dim3(20, 20, 4), dim3(32, 8), 0, stream>>>(wq, wk, wv, wo, WT, flag);

  // Q projection (scale folded): BM=64/BN=160 -> 1024 blocks = 4/CU (2x TLP vs r15)
  gemm2q<<<dim3(256, 4), 256, 0, stream>>>(hs, WT, Qb, QSCALE, flag);
  // K and V (V transposed + key-permuted): r11-proven reg-staged body
  gemm_kv<<<dim3(8, 5, 4), 256, 0, stream>>>(hs, WT + 409600, WT + 819200, Kb, Vb, flag);

  attn_kernel<<<dim3(8, 128), 256, 0, stream>>>(Qb, Kb, Vb, AOb);

  // output projection + bias (bf16 A -> gload_lds is a pure win here)
  gemm3<<<dim3(128, 5), 256, 0, stream>>>(AOb, WT + 1228800, d_out, 1.f, bo, flag, 0, 1);
}